// Round 18
// baseline (98.736 us; speedup 1.0000x reference)
//
#include <hip/hip_runtime.h>
#include <cstdint>
#include <cstddef>

#define HW_N   262144       // 512*512 elements per (b,c) map
#define ROWS   128          // 32*4 maps
#define NCHUNK 256          // 1024-elem chunks per row (one wave-shot each: 64 lanes x 16)

__device__ __forceinline__ void block_reduce_add(double v, double* target, int tid) {
    #pragma unroll
    for (int o = 32; o > 0; o >>= 1) v += __shfl_down(v, o);
    __shared__ double sred[16];
    const int lane = tid & 63, wave = tid >> 6;
    if (lane == 0) sred[wave] = v;
    __syncthreads();
    if (tid == 0) {
        double s = 0.0;
        const int nw = blockDim.x >> 6;
        for (int w = 0; w < nw; ++w) s += sred[w];
        atomicAdd(target, s);
    }
}

// ---- pass 1: t -> 16-bit masks + per-1024-chunk positive counts ----
__global__ __launch_bounds__(1024) void count_kernel(
        const int4* __restrict__ t4, unsigned short* __restrict__ mask16,
        int* __restrict__ chunkcnt) {
    const int blk = blockIdx.x;                 // 1024 blocks, 32768 elems each
    const size_t e0 = (size_t)blk * 32768;
    const int tid = threadIdx.x;
    const int lane = tid & 63, wave = tid >> 6; // 16 waves; wave's 64x16 = one chunk
    #pragma unroll
    for (int it = 0; it < 2; ++it) {
        const int g = it * 1024 + tid;          // 16-elem group index within block
        const size_t b4 = e0 / 4 + 4 * (size_t)g;
        const int4 a = t4[b4], b = t4[b4 + 1], c = t4[b4 + 2], d = t4[b4 + 3];
        const unsigned m =
            (unsigned)(a.x > 0)         | ((unsigned)(a.y > 0) << 1)  |
            ((unsigned)(a.z > 0) << 2)  | ((unsigned)(a.w > 0) << 3)  |
            ((unsigned)(b.x > 0) << 4)  | ((unsigned)(b.y > 0) << 5)  |
            ((unsigned)(b.z > 0) << 6)  | ((unsigned)(b.w > 0) << 7)  |
            ((unsigned)(c.x > 0) << 8)  | ((unsigned)(c.y > 0) << 9)  |
            ((unsigned)(c.z > 0) << 10) | ((unsigned)(c.w > 0) << 11) |
            ((unsigned)(d.x > 0) << 12) | ((unsigned)(d.y > 0) << 13) |
            ((unsigned)(d.z > 0) << 14) | ((unsigned)(d.w > 0) << 15);
        mask16[e0 / 16 + g] = (unsigned short)m;
        int cnt = __popc(m);
        #pragma unroll
        for (int o = 32; o > 0; o >>= 1) cnt += __shfl_down(cnt, o);
        if (lane == 0) chunkcnt[blk * 32 + it * 16 + wave] = cnt;
    }
}

// ---- pass 2: per-row exclusive scan of 256 chunk counts -> chunkoff, k ----
__global__ __launch_bounds__(256) void offsets_kernel(
        const int* __restrict__ chunkcnt, int* __restrict__ chunkoff,
        int* __restrict__ kArr, double* __restrict__ acc) {
    const int row = blockIdx.x;
    const int tid = threadIdx.x;
    const int lane = tid & 63, wave = tid >> 6;   // 4 waves
    const int c = chunkcnt[row * NCHUNK + tid];
    int incl = c;
    #pragma unroll
    for (int o = 1; o < 64; o <<= 1) {
        const int u = __shfl_up(incl, o);
        if (lane >= o) incl += u;
    }
    __shared__ int wt[4];
    if (lane == 63) wt[wave] = incl;
    __syncthreads();
    int wpre = 0;
    #pragma unroll
    for (int w = 0; w < 4; ++w) wpre += (w < wave) ? wt[w] : 0;
    chunkoff[row * NCHUNK + tid] = wpre + incl - c;
    if (tid == NCHUNK - 1) {
        const int k = wpre + incl;
        kArr[row] = k < 1 ? 1 : k;      // true positive count (>=1 per reference)
    }
    if (blockIdx.x == 0 && tid < 2) acc[tid] = 0.0;
}

// ---- pass 3: fused CE + sim(A,B). 1024-chunks, LDS densify, branchless pair rounds.
// Positive rank m serves j = m + i*k while j < N (bijection onto [0,N)).
// CE's -t*v term is folded into dense rounds as -v per positive.
__global__ __launch_bounds__(256) void fused_kernel(
        const float4* __restrict__ x4, const unsigned short* __restrict__ mask16,
        const int* __restrict__ chunkoff, const int* __restrict__ kArr,
        double* __restrict__ acc) {
    const int blk   = blockIdx.x;           // 4096 blocks, 8 chunks each
    const int row   = blk >> 5;             // 32 blocks/row
    const int bpart = blk & 31;
    const float*  xr  = (const float*)x4 + (size_t)row * HW_N;
    const float4* xr4 = x4 + (size_t)row * (HW_N / 4);
    const unsigned char* mr8 = (const unsigned char*)(mask16 + (size_t)row * (HW_N / 16));
    const unsigned short* mr16 = mask16 + (size_t)row * (HW_N / 16);
    const int* cor = chunkoff + row * NCHUNK;
    const int k    = kArr[row];
    const int Nmk  = HW_N - k;              // m <  Nmk  -> has copy 1
    const int Nm2k = HW_N - 2 * k;          // m <  Nm2k -> has copy 2 (rare region)

    const int tid  = threadIdx.x;
    const int lane = tid & 63;
    const int wave = tid >> 6;              // 0..3

    __shared__ float lbuf[4][1024];         // per-wave private compaction buffer (16 KB)
    float* wb = lbuf[wave];

    // branchless positive core: copy0 unconditional, copy1 predicated via clamp+cndmask.
    // Emits linear terms into AF; log-product factor into PR (caller takes one log).
    #define CORE(P, AF, PR) { \
        const float v  = wb[P]; \
        const int   m  = cbase + (P); \
        const float eB = 1.0f + __expf(-fabsf(v)); \
        const float nB = fmaxf(-v, 0.0f); \
        const float x0 = xr[m]; \
        const unsigned b0 = (mr8[m >> 3] >> (m & 7)) & 1; \
        const float dx0 = v * x0; \
        const float s0  = b0 ? fmaxf(-dx0, 0.0f) : fmaxf(dx0, 0.0f); \
        const float p0  = 1.0f + __expf(-fabsf(dx0)); \
        const bool  ex  = (m < Nmk); \
        const int   j1  = ex ? m + k : m; \
        const float x1  = xr[j1]; \
        const unsigned b1 = (mr8[j1 >> 3] >> (j1 & 7)) & 1; \
        const float dx1 = v * x1; \
        const float s1r = b1 ? fmaxf(-dx1, 0.0f) : fmaxf(dx1, 0.0f); \
        const float p1r = 1.0f + __expf(-fabsf(dx1)); \
        const float s1  = ex ? (s1r + nB) : 0.0f; \
        const float p1  = ex ? (p1r * eB) : 1.0f; \
        AF += (nB - v) + s0 + s1; \
        PR  = (PR) * (eB * p0 * p1); \
    }

    double dtot = 0.0;                      // CE + A + B (equal weight, ALPHA=0.5)
    #pragma unroll
    for (int i = 0; i < 2; ++i) {
        const int rc = bpart * 8 + i * 4 + wave;    // row-chunk id (0..255)
        const int j0 = rc * 1024 + lane * 16;        // element within row
        const float4 a  = xr4[j0 / 4],     b  = xr4[j0 / 4 + 1];
        const float4 cc = xr4[j0 / 4 + 2], dd = xr4[j0 / 4 + 3];
        const unsigned mb = mr16[j0 >> 4];

        // ---- CE on 16 owned elements (selects removed; -t*v folded into rounds) ----
        float af = 0.0f;
        float prod = 1.0f;
        #define CE(s, v) { \
            af += fmaxf(v, 0.0f); \
            prod *= 1.0f + __expf(-fabsf(v)); }
        CE(0, a.x)  CE(1, a.y)  CE(2, a.z)  CE(3, a.w)
        CE(4, b.x)  CE(5, b.y)  CE(6, b.z)  CE(7, b.w)
        CE(8, cc.x) CE(9, cc.y) CE(10, cc.z) CE(11, cc.w)
        CE(12, dd.x) CE(13, dd.y) CE(14, dd.z) CE(15, dd.w)
        #undef CE
        af += __logf(prod);                 // prod in [1, 65536] -> fine

        // ---- exclusive scan of per-lane popcounts -> slot base ----
        const int cnt = __popc(mb);
        int incl = cnt;
        #pragma unroll
        for (int o = 1; o < 64; o <<= 1) {
            const int u = __shfl_up(incl, o);
            if (lane >= o) incl += u;
        }
        const int base  = incl - cnt;
        const int total = __shfl(incl, 63);

        // ---- compact positive values into wave-private LDS ----
        {
            int r = base;
            #define ST(s, v) if ((mb >> s) & 1) { wb[r] = v; ++r; }
            ST(0, a.x)  ST(1, a.y)  ST(2, a.z)  ST(3, a.w)
            ST(4, b.x)  ST(5, b.y)  ST(6, b.z)  ST(7, b.w)
            ST(8, cc.x) ST(9, cc.y) ST(10, cc.z) ST(11, cc.w)
            ST(12, dd.x) ST(13, dd.y) ST(14, dd.z) ST(15, dd.w)
            #undef ST
        }

        // ---- dense rounds: paired 2x ILP, one log per pair; single-round tail ----
        const int cbase = cor[rc];
        if (cbase >= Nm2k) {
            float af1 = 0.0f;
            const int npair = total & ~127;
            int p = lane;
            for (; p < npair; p += 128) {
                float prA = 1.0f, prB = 1.0f;
                CORE(p, af, prA)
                CORE(p + 64, af1, prB)
                af += __logf(prA * prB);    // <= 2^12, exact to fp32
            }
            for (; p < total; p += 64) {
                float prA = 1.0f;
                CORE(p, af, prA)
                af += __logf(prA);
            }
            af += af1;
        } else {
            // rare region (first ~2 chunks per row): general per-positive loop
            for (int p = lane; p < total; p += 64) {
                const float v = wb[p];
                const int m = cbase + p;
                const float eB = 1.0f + __expf(-fabsf(v));
                const float nB = fmaxf(-v, 0.0f);
                float s = -v;
                float pr = 1.0f;
                int cop = 0;
                for (int j = m; j < HW_N; j += k) {
                    const float dx = v * xr[j];
                    const unsigned tt = (mr8[j >> 3] >> (j & 7)) & 1;
                    s += tt ? fmaxf(-dx, 0.0f) : fmaxf(dx, 0.0f);
                    pr *= 1.0f + __expf(-fabsf(dx));
                    ++cop;
                }
                af += s + (float)cop * (nB + __logf(eB)) + __logf(pr);
            }
        }
        dtot += (double)af;
    }
    block_reduce_add(dtot, &acc[0], tid);
    #undef CORE
}

__global__ void finalize_kernel(const double* __restrict__ acc, float* __restrict__ out) {
    if (threadIdx.x == 0 && blockIdx.x == 0) {
        const double inv = 1.0 / 33554432.0;    // 1 / (ROWS * HW_N)
        out[0] = (float)(0.5 * acc[0] * inv);   // ALPHA=0.5: equal weights, single sum
    }
}

extern "C" void kernel_launch(void* const* d_in, const int* in_sizes, int n_in,
                              void* d_out, int out_size, void* d_ws, size_t ws_size,
                              hipStream_t stream) {
    const float* x = (const float*)d_in[0];
    const int*   t = (const int*)d_in[1];
    float* out = (float*)d_out;

    // workspace layout (<= 13 MB):
    //   [0,16)           f64 accumulator(s)
    //   [16384,16896)    kArr      (ROWS ints)
    //   [32768, +4MB)    mask16    (ROWS*HW_N/16 ushorts)
    //   [8MB, +128KB)    chunkcnt  (ROWS*NCHUNK ints)
    //   [12MB, +128KB)   chunkoff  (ROWS*NCHUNK ints)
    double*         acc      = (double*)d_ws;
    int*            kArr     = (int*)((char*)d_ws + 16384);
    unsigned short* mask16   = (unsigned short*)((char*)d_ws + 32768);
    int*            chunkcnt = (int*)((char*)d_ws + (8u << 20));
    int*            chunkoff = (int*)((char*)d_ws + (12u << 20));

    count_kernel   <<<1024, 1024, 0, stream>>>((const int4*)t, mask16, chunkcnt);
    offsets_kernel <<<ROWS, 256, 0, stream>>>(chunkcnt, chunkoff, kArr, acc);
    fused_kernel   <<<ROWS * 32, 256, 0, stream>>>((const float4*)x, mask16, chunkoff, kArr, acc);
    finalize_kernel<<<1, 64, 0, stream>>>(acc, out);
}

// Round 19
// 85.120 us; speedup vs baseline: 1.1600x; 1.1600x over previous
//
#include <hip/hip_runtime.h>
#include <cstdint>
#include <cstddef>

#define HW_N   262144       // 512*512 elements per (b,c) map
#define ROWS   128          // 32*4 maps
#define NCHUNK 256          // 1024-elem chunks per row (one wave-shot each: 64 lanes x 16)

__device__ __forceinline__ void block_reduce_add(double v, double* target, int tid) {
    #pragma unroll
    for (int o = 32; o > 0; o >>= 1) v += __shfl_down(v, o);
    __shared__ double sred[16];
    const int lane = tid & 63, wave = tid >> 6;
    if (lane == 0) sred[wave] = v;
    __syncthreads();
    if (tid == 0) {
        double s = 0.0;
        const int nw = blockDim.x >> 6;
        for (int w = 0; w < nw; ++w) s += sred[w];
        atomicAdd(target, s);
    }
}

// ---- pass 1: t -> 16-bit masks + per-1024-chunk positive counts ----
__global__ __launch_bounds__(1024) void count_kernel(
        const int4* __restrict__ t4, unsigned short* __restrict__ mask16,
        int* __restrict__ chunkcnt) {
    const int blk = blockIdx.x;                 // 1024 blocks, 32768 elems each
    const size_t e0 = (size_t)blk * 32768;
    const int tid = threadIdx.x;
    const int lane = tid & 63, wave = tid >> 6; // 16 waves; wave's 64x16 = one chunk
    #pragma unroll
    for (int it = 0; it < 2; ++it) {
        const int g = it * 1024 + tid;          // 16-elem group index within block
        const size_t b4 = e0 / 4 + 4 * (size_t)g;
        const int4 a = t4[b4], b = t4[b4 + 1], c = t4[b4 + 2], d = t4[b4 + 3];
        const unsigned m =
            (unsigned)(a.x > 0)         | ((unsigned)(a.y > 0) << 1)  |
            ((unsigned)(a.z > 0) << 2)  | ((unsigned)(a.w > 0) << 3)  |
            ((unsigned)(b.x > 0) << 4)  | ((unsigned)(b.y > 0) << 5)  |
            ((unsigned)(b.z > 0) << 6)  | ((unsigned)(b.w > 0) << 7)  |
            ((unsigned)(c.x > 0) << 8)  | ((unsigned)(c.y > 0) << 9)  |
            ((unsigned)(c.z > 0) << 10) | ((unsigned)(c.w > 0) << 11) |
            ((unsigned)(d.x > 0) << 12) | ((unsigned)(d.y > 0) << 13) |
            ((unsigned)(d.z > 0) << 14) | ((unsigned)(d.w > 0) << 15);
        mask16[e0 / 16 + g] = (unsigned short)m;
        int cnt = __popc(m);
        #pragma unroll
        for (int o = 32; o > 0; o >>= 1) cnt += __shfl_down(cnt, o);
        if (lane == 0) chunkcnt[blk * 32 + it * 16 + wave] = cnt;
    }
}

// ---- pass 2: per-row exclusive scan of 256 chunk counts -> chunkoff, k ----
__global__ __launch_bounds__(256) void offsets_kernel(
        const int* __restrict__ chunkcnt, int* __restrict__ chunkoff,
        int* __restrict__ kArr, double* __restrict__ acc) {
    const int row = blockIdx.x;
    const int tid = threadIdx.x;
    const int lane = tid & 63, wave = tid >> 6;   // 4 waves
    const int c = chunkcnt[row * NCHUNK + tid];
    int incl = c;
    #pragma unroll
    for (int o = 1; o < 64; o <<= 1) {
        const int u = __shfl_up(incl, o);
        if (lane >= o) incl += u;
    }
    __shared__ int wt[4];
    if (lane == 63) wt[wave] = incl;
    __syncthreads();
    int wpre = 0;
    #pragma unroll
    for (int w = 0; w < 4; ++w) wpre += (w < wave) ? wt[w] : 0;
    chunkoff[row * NCHUNK + tid] = wpre + incl - c;
    if (tid == NCHUNK - 1) {
        const int k = wpre + incl;
        kArr[row] = k < 1 ? 1 : k;      // true positive count (>=1 per reference)
    }
    if (blockIdx.x == 0 && tid < 2) acc[tid] = 0.0;
}

// ---- pass 3: fused CE + sim(A,B). 1024-chunks, LDS densify, branchless paired rounds.
// Positive rank m serves j = m + i*k while j < N (bijection onto [0,N)).
// CE's -t*v term is folded into dense rounds as -v per positive.
__global__ __launch_bounds__(256) void fused_kernel(
        const float4* __restrict__ x4, const unsigned short* __restrict__ mask16,
        const int* __restrict__ chunkoff, const int* __restrict__ kArr,
        double* __restrict__ acc) {
    const int blk   = blockIdx.x;           // 2048 blocks, 16 chunks each
    const int row   = blk >> 4;             // 16 blocks/row
    const int bpart = blk & 15;
    const float*  xr  = (const float*)x4 + (size_t)row * HW_N;
    const float4* xr4 = x4 + (size_t)row * (HW_N / 4);
    const unsigned char* mr8 = (const unsigned char*)(mask16 + (size_t)row * (HW_N / 16));
    const unsigned short* mr16 = mask16 + (size_t)row * (HW_N / 16);
    const int* cor = chunkoff + row * NCHUNK;
    const int k    = kArr[row];
    const int Nmk  = HW_N - k;              // m <  Nmk  -> has copy 1
    const int Nm2k = HW_N - 2 * k;          // m <  Nm2k -> has copy 2 (rare region)

    const int tid  = threadIdx.x;
    const int lane = tid & 63;
    const int wave = tid >> 6;              // 0..3

    __shared__ float lbuf[4][1024];         // per-wave private compaction buffer (16 KB)
    float* wb = lbuf[wave];

    // branchless positive: copy0 unconditional, copy1 predicated via clamp+cndmask.
    // B-term count = 1 + ex; CE correction -v.
    #define FAST(P, AF) { \
        const float v  = wb[P]; \
        const int   m  = cbase + (P); \
        const float eB = 1.0f + __expf(-fabsf(v)); \
        const float nB = fmaxf(-v, 0.0f); \
        const float x0 = xr[m]; \
        const unsigned b0 = (mr8[m >> 3] >> (m & 7)) & 1; \
        const float dx0 = v * x0; \
        const float s0  = b0 ? fmaxf(-dx0, 0.0f) : fmaxf(dx0, 0.0f); \
        const float p0  = 1.0f + __expf(-fabsf(dx0)); \
        const bool  ex  = (m < Nmk); \
        const int   j1  = ex ? m + k : m; \
        const float x1  = xr[j1]; \
        const unsigned b1 = (mr8[j1 >> 3] >> (j1 & 7)) & 1; \
        const float dx1 = v * x1; \
        const float s1r = b1 ? fmaxf(-dx1, 0.0f) : fmaxf(dx1, 0.0f); \
        const float p1r = 1.0f + __expf(-fabsf(dx1)); \
        const float s1  = ex ? (s1r + nB) : 0.0f; \
        const float p1  = ex ? (p1r * eB) : 1.0f; \
        AF += (nB - v) + s0 + s1 + __logf(eB * p0 * p1); \
    }

    double dtot = 0.0;                      // CE + A + B (equal weight, ALPHA=0.5)
    #pragma unroll
    for (int i = 0; i < 4; ++i) {
        const int rc = bpart * 16 + i * 4 + wave;   // row-chunk id (0..255)
        const int j0 = rc * 1024 + lane * 16;        // element within row
        const float4 a  = xr4[j0 / 4],     b  = xr4[j0 / 4 + 1];
        const float4 cc = xr4[j0 / 4 + 2], dd = xr4[j0 / 4 + 3];
        const unsigned mb = mr16[j0 >> 4];

        // ---- CE on 16 owned elements (selects removed; -t*v folded into rounds) ----
        float af = 0.0f;
        float prod = 1.0f;
        #define CE(s, v) { \
            af += fmaxf(v, 0.0f); \
            prod *= 1.0f + __expf(-fabsf(v)); }
        CE(0, a.x)  CE(1, a.y)  CE(2, a.z)  CE(3, a.w)
        CE(4, b.x)  CE(5, b.y)  CE(6, b.z)  CE(7, b.w)
        CE(8, cc.x) CE(9, cc.y) CE(10, cc.z) CE(11, cc.w)
        CE(12, dd.x) CE(13, dd.y) CE(14, dd.z) CE(15, dd.w)
        #undef CE
        af += __logf(prod);                 // prod in [1, 65536] -> fine

        // ---- exclusive scan of per-lane popcounts -> slot base ----
        const int cnt = __popc(mb);
        int incl = cnt;
        #pragma unroll
        for (int o = 1; o < 64; o <<= 1) {
            const int u = __shfl_up(incl, o);
            if (lane >= o) incl += u;
        }
        const int base  = incl - cnt;
        const int total = __shfl(incl, 63);

        // ---- compact positive values into wave-private LDS ----
        {
            int r = base;
            #define ST(s, v) if ((mb >> s) & 1) { wb[r] = v; ++r; }
            ST(0, a.x)  ST(1, a.y)  ST(2, a.z)  ST(3, a.w)
            ST(4, b.x)  ST(5, b.y)  ST(6, b.z)  ST(7, b.w)
            ST(8, cc.x) ST(9, cc.y) ST(10, cc.z) ST(11, cc.w)
            ST(12, dd.x) ST(13, dd.y) ST(14, dd.z) ST(15, dd.w)
            #undef ST
        }

        // ---- dense rounds ----
        const int cbase = cor[rc];
        if (cbase >= Nm2k) {
            // fast: copies in {1,2}, branchless bodies -> real 2x ILP pairing
            float af1 = 0.0f;
            const int nfull = total & ~127;
            int p = lane;
            for (; p < nfull; p += 128) {
                FAST(p, af)
                FAST(p + 64, af1)
            }
            for (; p < total; p += 64) {
                FAST(p, af)
            }
            af += af1;
        } else {
            // rare region (first ~2 chunks per row): general per-positive loop
            for (int p = lane; p < total; p += 64) {
                const float v = wb[p];
                const int m = cbase + p;
                const float eB = 1.0f + __expf(-fabsf(v));
                const float nB = fmaxf(-v, 0.0f);
                float s = -v;
                float pr = 1.0f;
                int cop = 0;
                for (int j = m; j < HW_N; j += k) {
                    const float dx = v * xr[j];
                    const unsigned tt = (mr8[j >> 3] >> (j & 7)) & 1;
                    s += tt ? fmaxf(-dx, 0.0f) : fmaxf(dx, 0.0f);
                    pr *= 1.0f + __expf(-fabsf(dx));
                    ++cop;
                }
                af += s + (float)cop * (nB + __logf(eB)) + __logf(pr);
            }
        }
        dtot += (double)af;
    }
    block_reduce_add(dtot, &acc[0], tid);
    #undef FAST
}

__global__ void finalize_kernel(const double* __restrict__ acc, float* __restrict__ out) {
    if (threadIdx.x == 0 && blockIdx.x == 0) {
        const double inv = 1.0 / 33554432.0;    // 1 / (ROWS * HW_N)
        out[0] = (float)(0.5 * acc[0] * inv);   // ALPHA=0.5: equal weights, single sum
    }
}

extern "C" void kernel_launch(void* const* d_in, const int* in_sizes, int n_in,
                              void* d_out, int out_size, void* d_ws, size_t ws_size,
                              hipStream_t stream) {
    const float* x = (const float*)d_in[0];
    const int*   t = (const int*)d_in[1];
    float* out = (float*)d_out;

    // workspace layout (<= 13 MB):
    //   [0,16)           f64 accumulator(s)
    //   [16384,16896)    kArr      (ROWS ints)
    //   [32768, +4MB)    mask16    (ROWS*HW_N/16 ushorts)
    //   [8MB, +128KB)    chunkcnt  (ROWS*NCHUNK ints)
    //   [12MB, +128KB)   chunkoff  (ROWS*NCHUNK ints)
    double*         acc      = (double*)d_ws;
    int*            kArr     = (int*)((char*)d_ws + 16384);
    unsigned short* mask16   = (unsigned short*)((char*)d_ws + 32768);
    int*            chunkcnt = (int*)((char*)d_ws + (8u << 20));
    int*            chunkoff = (int*)((char*)d_ws + (12u << 20));

    count_kernel   <<<1024, 1024, 0, stream>>>((const int4*)t, mask16, chunkcnt);
    offsets_kernel <<<ROWS, 256, 0, stream>>>(chunkcnt, chunkoff, kArr, acc);
    fused_kernel   <<<ROWS * 16, 256, 0, stream>>>((const float4*)x, mask16, chunkoff, kArr, acc);
    finalize_kernel<<<1, 64, 0, stream>>>(acc, out);
}